// Round 3
// baseline (263.401 us; speedup 1.0000x reference)
//
#include <hip/hip_runtime.h>

#define N_SAMP   1024
#define IN_F     512
#define OUT_F    512
#define N_HEADS  32
#define N_SPLITS 4
#define N_GROUPS (N_HEADS * N_SPLITS)
#define DELTA_SCALE 0.1f

// R8: row-contiguous W/D streaming with LDS-staged combined weights.
//   block = (combo g, col-half ch, sample-parity sg)  grid = (4, 128) = 512
//   Each block owns 256 CONTIGUOUS cols x all 512 k-rows of W[h], D[g].
//   Per 8-row step the block cooperatively streams 8 KB W + 8 KB D as
//   1KB-contiguous per-wave dwordx4 bursts (vs R7's 256B segments at 2KB
//   stride scattered over 8 blocks -> HBM row-buffer thrash at 1.07 TB/s).
//   rc = w + 0.1*d is combined in-register and staged into a double-buffered
//   LDS tile (one barrier/step; distance-1 reg prefetch: loads for t+1
//   issue BEFORE consuming t, so the compiler emits counted vmcnt waits).
//   No k-split: each thread owns (2 cols x 4 samples) and its acc is final
//   -> no Red round-trip, no atomics; out written once, bias folded in.
//   sg is a stride-2 sample split (both sg blocks active at the mean-8
//   combo size -- no early-exit occupancy holes).
__global__ __launch_bounds__(256, 2) void lms_rowstream(
    const float* __restrict__ X, const int* __restrict__ head_ix,
    const int* __restrict__ split_ix, const float* __restrict__ W,
    const float* __restrict__ D, const float* __restrict__ bias,
    float* __restrict__ out)
{
    constexpr int J    = 8;             // samples per chunk (per sg)
    constexpr int NSG  = 2;             // stride-interleaved sample split
    constexpr int HC   = 256;           // cols per block
    constexpr int RPS  = 8;             // rows per step
    constexpr int NST  = IN_F / RPS;    // 64 steps

    __shared__ float Xs[J][IN_F];       // 16 KB, zero-padded invalid rows
    __shared__ float rcb[2][RPS][HC];   // 16 KB, double-buffered rc tile
    __shared__ int   list[N_SAMP];      // 4 KB
    __shared__ int   wsum[4];

    const int g    = blockIdx.y;            // combo = h*N_SPLITS + s
    const int h    = g >> 2;                // N_SPLITS == 4
    const int sg   = blockIdx.x & 1;
    const int ch   = blockIdx.x >> 1;
    const int c0   = ch * HC;
    const int tid  = threadIdx.x;
    const int c2   = tid & 127;             // col pair within the 256-col half
    const int jh   = tid >> 7;              // sample-half (wave-uniform)
    const int lane = tid & 63;
    const int wave = tid >> 6;

    // deterministic order-preserving compaction of samples matching combo g
    int run = 0;
    for (int r = 0; r < N_SAMP / 256; ++r) {
        const int i   = r * 256 + tid;
        const int key = head_ix[i] * N_SPLITS + split_ix[i];
        const bool hit = (key == g);
        const unsigned long long m = __ballot(hit);
        if (lane == 0) wsum[wave] = __popcll(m);
        __syncthreads();
        int base = run;
        for (int w = 0; w < 4; ++w)
            if (w < wave) base += wsum[w];
        if (hit)
            list[base + __popcll(m & ((1ULL << lane) - 1ULL))] = i;
        run += wsum[0] + wsum[1] + wsum[2] + wsum[3];
        __syncthreads();               // wsum consumed before next round
    }
    const int total = run;
    // this sg's samples: positions sg, sg+2, sg+4, ...
    const int cnt = (total > sg) ? ((total - 1 - sg) / NSG + 1) : 0;
    if (cnt == 0) return;              // block-uniform

    const float* wbase = W + (size_t)h * (IN_F * OUT_F) + c0;
    const float* dbase = D + (size_t)g * (IN_F * OUT_F) + c0;
    const float2 bv = *(const float2*)(bias + (size_t)h * OUT_F + c0 + 2 * c2);

    for (int cb = 0; cb < cnt; cb += J) {
        const int nc = min(cnt - cb, J);

        __syncthreads();               // Xs/rcb fully consumed by prev chunk
        // stage X rows (gathered; 1KB-contiguous per wave within a row)
        for (int f = 0; f < 4; ++f) {
            const int fid = f * 256 + tid;
            const int s = fid >> 7, q = fid & 127;
            float4 v = make_float4(0.f, 0.f, 0.f, 0.f);
            if (s < nc)
                v = *(const float4*)(X + (size_t)list[sg + NSG * (cb + s)] * IN_F + q * 4);
            *(float4*)(&Xs[s][q * 4]) = v;
        }
        // NOTE: no barrier needed yet -- first compute is after barrier(t=0)

        float2 acc[4];
#pragma unroll
        for (int jj = 0; jj < 4; ++jj) { acc[jj].x = 0.f; acc[jj].y = 0.f; }

        // staging slots: fid = f*256 + tid -> row r = fid>>6, col4 = (fid&63)*4
        const int r0 = tid >> 6,        cc0 = (tid & 63) << 2;       // f=0
        const int r1 = (256 + tid) >> 6, cc1 = cc0;                  // f=1
        float4 wrg[2][2], drg[2][2];

        // prolog: issue L(0)
        {
            const float* wp = wbase;
            const float* dp = dbase;
            wrg[0][0] = *(const float4*)(wp + (size_t)r0 * OUT_F + cc0);
            wrg[0][1] = *(const float4*)(wp + (size_t)r1 * OUT_F + cc1);
            drg[0][0] = *(const float4*)(dp + (size_t)r0 * OUT_F + cc0);
            drg[0][1] = *(const float4*)(dp + (size_t)r1 * OUT_F + cc1);
        }

#pragma unroll 2
        for (int t = 0; t < NST; ++t) {
            const int cur = t & 1, nxt = cur ^ 1;
            const int k0 = t * RPS;

            // 1. issue L(t+1) (before consuming L(t) -> counted vmcnt)
            if (t + 1 < NST) {
                const float* wp = wbase + (size_t)(k0 + RPS) * OUT_F;
                const float* dp = dbase + (size_t)(k0 + RPS) * OUT_F;
                wrg[nxt][0] = *(const float4*)(wp + (size_t)r0 * OUT_F + cc0);
                wrg[nxt][1] = *(const float4*)(wp + (size_t)r1 * OUT_F + cc1);
                drg[nxt][0] = *(const float4*)(dp + (size_t)r0 * OUT_F + cc0);
                drg[nxt][1] = *(const float4*)(dp + (size_t)r1 * OUT_F + cc1);
            }

            // 2. combine rc(t) = w + 0.1*d, stage into rcb[cur]
            {
                float4 a = wrg[cur][0], b = drg[cur][0];
                float4 rc0 = make_float4(a.x + DELTA_SCALE * b.x,
                                         a.y + DELTA_SCALE * b.y,
                                         a.z + DELTA_SCALE * b.z,
                                         a.w + DELTA_SCALE * b.w);
                *(float4*)(&rcb[cur][r0][cc0]) = rc0;
                a = wrg[cur][1]; b = drg[cur][1];
                float4 rc1 = make_float4(a.x + DELTA_SCALE * b.x,
                                         a.y + DELTA_SCALE * b.y,
                                         a.z + DELTA_SCALE * b.z,
                                         a.w + DELTA_SCALE * b.w);
                *(float4*)(&rcb[cur][r1][cc1]) = rc1;
            }

            // 3. one barrier per step: rcb[cur] globally visible; laggards
            //    finished reading rcb[cur] two phases ago (dbuf distance)
            __syncthreads();

            // 4. compute step t from rcb[cur] + Xs broadcast
            float2 rr[RPS];
#pragma unroll
            for (int r = 0; r < RPS; ++r)
                rr[r] = *(const float2*)(&rcb[cur][r][2 * c2]);
#pragma unroll
            for (int jj = 0; jj < 4; ++jj) {
                const int j = jh * 4 + jj;
                const float4 xa = *(const float4*)(&Xs[j][k0]);      // bcast
                const float4 xb = *(const float4*)(&Xs[j][k0 + 4]);  // bcast
                acc[jj].x += xa.x * rr[0].x; acc[jj].y += xa.x * rr[0].y;
                acc[jj].x += xa.y * rr[1].x; acc[jj].y += xa.y * rr[1].y;
                acc[jj].x += xa.z * rr[2].x; acc[jj].y += xa.z * rr[2].y;
                acc[jj].x += xa.w * rr[3].x; acc[jj].y += xa.w * rr[3].y;
                acc[jj].x += xb.x * rr[4].x; acc[jj].y += xb.x * rr[4].y;
                acc[jj].x += xb.y * rr[5].x; acc[jj].y += xb.y * rr[5].y;
                acc[jj].x += xb.z * rr[6].x; acc[jj].y += xb.z * rr[6].y;
                acc[jj].x += xb.w * rr[7].x; acc[jj].y += xb.w * rr[7].y;
            }
        }

        // epilogue: acc is final (no k-split) -> direct store, bias folded
#pragma unroll
        for (int jj = 0; jj < 4; ++jj) {
            const int i = cb + jh * 4 + jj;
            if (i < cnt) {
                float* op = out + (size_t)list[sg + NSG * i] * OUT_F + c0 + 2 * c2;
                float2 res;
                res.x = acc[jj].x + bv.x;
                res.y = acc[jj].y + bv.y;
                *(float2*)op = res;
            }
        }
    }
}

extern "C" void kernel_launch(void* const* d_in, const int* in_sizes, int n_in,
                              void* d_out, int out_size, void* d_ws, size_t ws_size,
                              hipStream_t stream) {
    const float* X        = (const float*)d_in[0];
    const int*   head_ix  = (const int*)d_in[1];
    const int*   split_ix = (const int*)d_in[2];
    const float* W        = (const float*)d_in[3];
    const float* D        = (const float*)d_in[4];
    const float* bias     = (const float*)d_in[5];
    float*       out      = (float*)d_out;

    // 128 combos x 2 col-halves x 2 sample-parities = 512 blocks = 2/CU
    // (36.4 KB LDS, ~90 VGPR). Single dispatch, out written exactly once.
    dim3 gf(4, N_GROUPS);
    lms_rowstream<<<gf, 256, 0, stream>>>(X, head_ix, split_ix, W, D, bias, out);
}